// Round 15
// baseline (344.317 us; speedup 1.0000x reference)
//
#include <hip/hip_runtime.h>

typedef unsigned long long u64;
typedef unsigned short u16;
typedef unsigned char u8;

#define NN 4096
#define NCH 64          // u64 chunks per bit-row
#define NSUP 6

// global pair key: (sim bits << 24) | (0xFFFFFF - triangular pair index)
__device__ __forceinline__ u64 gkey(int v, int u, unsigned sb) {
  int i = v < u ? v : u, j = v < u ? u : v;
  unsigned idx = (unsigned)i * (unsigned)(2 * NN - i - 1) / 2u + (unsigned)(j - i - 1);
  return ((u64)sb << 24) | (u64)(0xFFFFFFu - idx);
}

// insert kk into sorted-descending {a0>=a1>=a2>=a3} (keys unique)
__device__ __forceinline__ void ins4(u64& a0, u64& a1, u64& a2, u64& a3, u64 kk) {
  bool g0 = kk > a0, g1 = kk > a1, g2 = kk > a2, g3 = kk > a3;
  a3 = g3 ? (g2 ? a2 : kk) : a3;
  a2 = g2 ? (g1 ? a1 : kk) : a2;
  a1 = g1 ? (g0 ? a0 : kk) : a1;
  a0 = g0 ? kk : a0;
}

// ========= pack A rows into bits + degree (ballot) + all init, fused =========
__global__ __launch_bounds__(256) void k_packdeg(const float* __restrict__ A,
                                                 u64* __restrict__ bits,
                                                 u16* __restrict__ deg,
                                                 float* out, int out_n,
                                                 int* comp, int* ncomp, int* mstcnt) {
  int t = threadIdx.x;
  int w = t >> 6, lane = t & 63;
  int row = blockIdx.x * 4 + w;
  const float* rp = A + (size_t)row * NN;
  u64 my = 0;
  int dsum = 0;
#pragma unroll 8
  for (int k = 0; k < 64; ++k) {
    float v = rp[k * 64 + lane];
    u64 m = __ballot(v > 0.0f);
    dsum += __popcll(m);
    if (lane == k) my = m;
  }
  bits[(size_t)row * NCH + lane] = my;
  if (lane == 0) deg[row] = (u16)dsum;
  int g = blockIdx.x * 256 + t;
  if (g < out_n) out[g] = 0.0f;            // out_n = 26148
  if (g < NN) comp[g] = g;
  if (g == 0) { *ncomp = NN; *mstcnt = 0; }
}

// ========== inter[i][j] = |N(i) & N(j)| via popcount GEMM (u8) ==========
// R8 shape + T14 async-stage: stage-1 global loads issued into registers
// BEFORE stage-0 compute; LDS write after barrier. Hides the exposed
// inter-stage global latency (the identified ~26% stall).
__global__ __launch_bounds__(256) void k_inter(const u64* __restrict__ bits,
                                               u8* __restrict__ inter) {
  __shared__ ulonglong2 L[2][64 * 16];   // 32 KiB total
  int b = blockIdx.x;
  int by = (int)((129.0f - sqrtf(16641.0f - 8.0f * (float)b)) * 0.5f) - 1;
  if (by < 0) by = 0;
#define CUM(y) (64 * (y) - ((y) * ((y) - 1)) / 2)
  while (by < 63 && CUM(by + 1) <= b) ++by;
  while (CUM(by) > b) --by;
  int bx = by + (b - CUM(by));
#undef CUM
  int i0 = by * 64, j0 = bx * 64;
  int t = threadIdx.x;
  int tx = t & 15, ty = t >> 4;
  int rowA[4], swA[4], rowB[4], swB[4];
#pragma unroll
  for (int a = 0; a < 4; ++a) {
    rowA[a] = ty * 4 + a; swA[a] = (rowA[a] ^ (rowA[a] >> 2)) & 7;
    rowB[a] = tx * 4 + a; swB[a] = (rowB[a] ^ (rowB[a] >> 2)) & 7;
  }
  int cuL = t & 15, rg = t >> 4;
  const ulonglong2* gi[4];
  const ulonglong2* gj[4];
  int swS[4];
#pragma unroll
  for (int rr = 0; rr < 4; ++rr) {
    int row = rg * 4 + rr;
    swS[rr] = (row ^ (row >> 2)) & 7;
    gi[rr] = reinterpret_cast<const ulonglong2*>(bits + (size_t)(i0 + row) * NCH);
    gj[rr] = reinterpret_cast<const ulonglong2*>(bits + (size_t)(j0 + row) * NCH);
  }
  ulonglong2 ra[4], rb[4];
#pragma unroll
  for (int rr = 0; rr < 4; ++rr) {       // stage-0 loads
    ra[rr] = gi[rr][cuL];
    rb[rr] = gj[rr][cuL];
  }
#pragma unroll
  for (int rr = 0; rr < 4; ++rr) {       // stage-0 LDS write
    int row = rg * 4 + rr;
    L[0][row * 16 + (cuL ^ swS[rr])] = ra[rr];
    L[1][row * 16 + (cuL ^ swS[rr])] = rb[rr];
  }
  __syncthreads();
#pragma unroll
  for (int rr = 0; rr < 4; ++rr) {       // stage-1 loads ISSUED EARLY (T14)
    ra[rr] = gi[rr][16 + cuL];
    rb[rr] = gj[rr][16 + cuL];
  }
  int acc[4][4] = {};
  for (int cu = 0; cu < 16; ++cu) {      // compute stage 0 (hides stage-1 latency)
    ulonglong2 av[4], bv[4];
#pragma unroll
    for (int a = 0; a < 4; ++a) av[a] = L[0][rowA[a] * 16 + (cu ^ swA[a])];
#pragma unroll
    for (int b2 = 0; b2 < 4; ++b2) bv[b2] = L[1][rowB[b2] * 16 + (cu ^ swB[b2])];
#pragma unroll
    for (int a = 0; a < 4; ++a)
#pragma unroll
      for (int b2 = 0; b2 < 4; ++b2)
        acc[a][b2] += __popcll(av[a].x & bv[b2].x) + __popcll(av[a].y & bv[b2].y);
  }
  __syncthreads();
#pragma unroll
  for (int rr = 0; rr < 4; ++rr) {       // stage-1 LDS write
    int row = rg * 4 + rr;
    L[0][row * 16 + (cuL ^ swS[rr])] = ra[rr];
    L[1][row * 16 + (cuL ^ swS[rr])] = rb[rr];
  }
  __syncthreads();
  for (int cu = 0; cu < 16; ++cu) {      // compute stage 1
    ulonglong2 av[4], bv[4];
#pragma unroll
    for (int a = 0; a < 4; ++a) av[a] = L[0][rowA[a] * 16 + (cu ^ swA[a])];
#pragma unroll
    for (int b2 = 0; b2 < 4; ++b2) bv[b2] = L[1][rowB[b2] * 16 + (cu ^ swB[b2])];
#pragma unroll
    for (int a = 0; a < 4; ++a)
#pragma unroll
      for (int b2 = 0; b2 < 4; ++b2)
        acc[a][b2] += __popcll(av[a].x & bv[b2].x) + __popcll(av[a].y & bv[b2].y);
  }
#pragma unroll
  for (int a = 0; a < 4; ++a) {          // direct tile [i][j]
    int i = i0 + ty * 4 + a;
    uchar4 wv;
    wv.x = (u8)acc[a][0]; wv.y = (u8)acc[a][1];
    wv.z = (u8)acc[a][2]; wv.w = (u8)acc[a][3];
    *reinterpret_cast<uchar4*>(inter + (size_t)i * NN + j0 + tx * 4) = wv;
  }
  if (bx != by) {
#pragma unroll
    for (int b2 = 0; b2 < 4; ++b2) {     // mirror tile [j][i]
      int j = j0 + tx * 4 + b2;
      uchar4 wv;
      wv.x = (u8)acc[0][b2]; wv.y = (u8)acc[1][b2];
      wv.z = (u8)acc[2][b2]; wv.w = (u8)acc[3][b2];
      *reinterpret_cast<uchar4*>(inter + (size_t)j * NN + i0 + ty * 4) = wv;
    }
  }
}

// ===== scan0: exact per-node TOP-4 list + phase-0 nkey/nu (one wave/row) =====
__global__ __launch_bounds__(256) void k_scan0(const u8* __restrict__ inter,
                                               const u16* __restrict__ deg,
                                               u64* __restrict__ tk,
                                               u64* __restrict__ nkey,
                                               int* __restrict__ nu) {
  __shared__ u16 deg_s[NN];    // 8 KiB
  int t = threadIdx.x;
  for (int i = t; i < NN / 8; i += 256)
    reinterpret_cast<uint4*>(deg_s)[i] = reinterpret_cast<const uint4*>(deg)[i];
  __syncthreads();
  int w = t >> 6, lane = t & 63;
  int v = blockIdx.x * 4 + w;
  int dv = (int)deg_s[v];
  const u8* row = inter + (size_t)v * NN;
  u64 a0 = 0, a1 = 0, a2 = 0, a3 = 0;
  for (int it = 0; it < 4; ++it) {
    int ub = it * 1024 + lane * 16;
    uint4 pv = *reinterpret_cast<const uint4*>(row + ub);              // 16x u8 inter
    uint4 dg0 = reinterpret_cast<const uint4*>(deg_s)[ub >> 3];
    uint4 dg1 = reinterpret_cast<const uint4*>(deg_s)[(ub >> 3) + 1];
    unsigned pw[4] = { pv.x, pv.y, pv.z, pv.w };
    unsigned dw[8] = { dg0.x, dg0.y, dg0.z, dg0.w, dg1.x, dg1.y, dg1.z, dg1.w };
#pragma unroll
    for (int k = 0; k < 16; ++k) {
      int u = ub + k;
      int iv = (int)((pw[k >> 2] >> ((k & 3) * 8)) & 0xFF);
      int du = (int)((dw[k >> 1] >> ((k & 1) * 16)) & 0xFFFF);
      int un = dv + du - iv;
      float s = (un > 0) ? ((float)iv / (float)un) : 0.0f;             // exact fp32 div == numpy
      u64 kk = (u != v)
                   ? (((u64)__float_as_uint(s) << 32) | (u64)(0xFFFFFFFFu - (unsigned)u))
                   : 0ull;
      ins4(a0, a1, a2, a3, kk);
    }
  }
#pragma unroll
  for (int off = 1; off < 64; off <<= 1) {   // wave butterfly merge of top4 lists
    u64 b0 = __shfl_xor(a0, off, 64);
    u64 b1 = __shfl_xor(a1, off, 64);
    u64 b2 = __shfl_xor(a2, off, 64);
    u64 b3 = __shfl_xor(a3, off, 64);
    ins4(a0, a1, a2, a3, b0);
    ins4(a0, a1, a2, a3, b1);
    ins4(a0, a1, a2, a3, b2);
    ins4(a0, a1, a2, a3, b3);
  }
  if (lane == 0) {
    u64* tv = tk + (size_t)v * 4;
    tv[0] = a0; tv[1] = a1; tv[2] = a2; tv[3] = a3;
    int u0 = (int)(0xFFFFFFFFu - (unsigned)(a0 & 0xFFFFFFFFull));
    nkey[v] = gkey(v, u0, (unsigned)(a0 >> 32));
    nu[v] = u0;
  }
}

// ===== loop scan (ph>=1): lean top-4 check vs global comp; stage only if stale =====
__global__ __launch_bounds__(256) void k_scan(const u8* __restrict__ inter,
                                              const u16* __restrict__ deg,
                                              const u64* __restrict__ tk,
                                              const int* __restrict__ comp,
                                              const int* __restrict__ ncomp,
                                              u64* __restrict__ nkey,
                                              int* __restrict__ nu) {
  if (*ncomp <= 1) return;
  __shared__ u16 comp_s[NN];   // 8 KiB (staged only when stale)
  __shared__ u16 deg_s[NN];    // 8 KiB
  __shared__ int needflag;
  int t = threadIdx.x;
  int w = t >> 6, lane = t & 63;
  int v = blockIdx.x * 4 + w;
  if (t == 0) needflag = 0;
  __syncthreads();
  if (lane == 0) {
    int cv = comp[v];
    const u64* tv = tk + (size_t)v * 4;
    u64 gk = 0; int bu = -1;
#pragma unroll
    for (int e = 0; e < 4; ++e) {
      u64 cand = tv[e];
      unsigned uu = 0xFFFFFFFFu - (unsigned)(cand & 0xFFFFFFFFull);
      if (bu < 0 && comp[uu] != cv) {
        bu = (int)uu;
        gk = gkey(v, (int)uu, (unsigned)(cand >> 32));
      }
    }
    if (bu >= 0) { nkey[v] = gk; nu[v] = bu; }
    else atomicOr(&needflag, 1 << w);
  }
  __syncthreads();
  int needmask = needflag;
  if (!needmask) return;
  // --- stale path: stage comp(u16)+deg, exact full-row rescan (R8 body) ---
  for (int i = t; i < NN / 8; i += 256) {
    int4 ca = reinterpret_cast<const int4*>(comp)[i * 2];
    int4 cb = reinterpret_cast<const int4*>(comp)[i * 2 + 1];
    uint4 pk;
    pk.x = (unsigned)ca.x | ((unsigned)ca.y << 16);
    pk.y = (unsigned)ca.z | ((unsigned)ca.w << 16);
    pk.z = (unsigned)cb.x | ((unsigned)cb.y << 16);
    pk.w = (unsigned)cb.z | ((unsigned)cb.w << 16);
    reinterpret_cast<uint4*>(comp_s)[i] = pk;
    reinterpret_cast<uint4*>(deg_s)[i] = reinterpret_cast<const uint4*>(deg)[i];
  }
  __syncthreads();
  if (!(needmask >> w & 1)) return;
  int cv = (int)comp_s[v];
  int dv = (int)deg_s[v];
  const u8* row = inter + (size_t)v * NN;
  u64 key = 0;
  for (int it = 0; it < 4; ++it) {
    int ub = it * 1024 + lane * 16;
    uint4 pv = *reinterpret_cast<const uint4*>(row + ub);              // 16x u8 inter
    uint4 dg0 = reinterpret_cast<const uint4*>(deg_s)[ub >> 3];
    uint4 dg1 = reinterpret_cast<const uint4*>(deg_s)[(ub >> 3) + 1];
    uint4 cs0 = reinterpret_cast<const uint4*>(comp_s)[ub >> 3];
    uint4 cs1 = reinterpret_cast<const uint4*>(comp_s)[(ub >> 3) + 1];
    unsigned pw[4] = { pv.x, pv.y, pv.z, pv.w };
    unsigned dw[8] = { dg0.x, dg0.y, dg0.z, dg0.w, dg1.x, dg1.y, dg1.z, dg1.w };
    unsigned cw[8] = { cs0.x, cs0.y, cs0.z, cs0.w, cs1.x, cs1.y, cs1.z, cs1.w };
#pragma unroll
    for (int k = 0; k < 16; ++k) {
      int iv = (int)((pw[k >> 2] >> ((k & 3) * 8)) & 0xFF);
      int du = (int)((dw[k >> 1] >> ((k & 1) * 16)) & 0xFFFF);
      int cu = (int)((cw[k >> 1] >> ((k & 1) * 16)) & 0xFFFF);
      int un = dv + du - iv;
      float s = (un > 0) ? ((float)iv / (float)un) : 0.0f;             // exact fp32 div == numpy
      u64 kk = (cu != cv)
                   ? (((u64)__float_as_uint(s) << 32) | (u64)(0xFFFFFFFFu - (unsigned)(ub + k)))
                   : 0ull;
      if (kk > key) key = kk;
    }
  }
#pragma unroll
  for (int off = 32; off > 0; off >>= 1) {                              // wave max-reduce
    unsigned lo = (unsigned)key, hi = (unsigned)(key >> 32);
    unsigned olo = __shfl_xor(lo, off, 64), ohi = __shfl_xor(hi, off, 64);
    u64 o = ((u64)ohi << 32) | (u64)olo;
    if (o > key) key = o;
  }
  if (lane == 0) {
    u64 pk = 0; int u = -1;
    if (key != 0ull) {
      unsigned simb = (unsigned)(key >> 32);
      u = (int)(0xFFFFFFFFu - (unsigned)(key & 0xFFFFFFFFull));
      pk = gkey(v, u, simb);
    }
    nkey[v] = pk; nu[v] = u;
  }
}

// ===== Boruvka merge: 1024 threads, COMPACT component ids (R14-proven) =====
__global__ __launch_bounds__(1024) void k_merge(const u64* __restrict__ nkey,
                                                const int* __restrict__ nu,
                                                int* comp, int* ncomp, int* mstcnt,
                                                u64* mkey, int* mi, int* mj,
                                                int* labels_g, float* invs_g, float* out) {
  int C = *ncomp;
  if (C <= 1) return;
  __shared__ int parent_s[NN];        // 16 KiB (finalize: p[])
  __shared__ u64 cbest_s[NN];         // 32 KiB (later: rank16/pre; finalize: rr/rk/rs)
  __shared__ u16 comp16s[NN];         // 8 KiB
  __shared__ u64 mark64[64];
  __shared__ int roots[16];
  __shared__ int rcnt, cnt_s, chg_s, changed;
  __shared__ int szs[8];
  __shared__ float ivs[8];
  int t = threadIdx.x;
  for (int i = t; i < NN / 8; i += 1024) {   // stage comp as u16
    int4 ca = reinterpret_cast<const int4*>(comp)[i * 2];
    int4 cb = reinterpret_cast<const int4*>(comp)[i * 2 + 1];
    uint4 pk;
    pk.x = (unsigned)ca.x | ((unsigned)ca.y << 16);
    pk.y = (unsigned)ca.z | ((unsigned)ca.w << 16);
    pk.z = (unsigned)cb.x | ((unsigned)cb.y << 16);
    pk.w = (unsigned)cb.z | ((unsigned)cb.w << 16);
    reinterpret_cast<uint4*>(comp16s)[i] = pk;
  }
  for (int c = t; c < C; c += 1024) { parent_s[c] = c; cbest_s[c] = 0ull; }
  __syncthreads();
  for (int v = t; v < NN; v += 1024) {
    u64 k = nkey[v];
    if (k) atomicMax(&cbest_s[(int)comp16s[v]], k);
  }
  __syncthreads();
  for (int v = t; v < NN; v += 1024) {
    u64 k = nkey[v];
    if (!k) continue;
    int c = (int)comp16s[v];
    if (k == cbest_s[c]) {
      int u = nu[v];
      int cu = (int)comp16s[u];
      bool mutual = (cbest_s[cu] == k);
      if (!mutual || v < u) {
        int slot = atomicAdd(mstcnt, 1);
        if (slot < 4352) { mkey[slot] = k; mi[slot] = v; mj[slot] = u; }
      }
      parent_s[c] = cu;                // one winner per component (keys unique)
    }
  }
  __syncthreads();
  for (int c = t; c < C; c += 1024) {  // break mutual 2-cycles: keep smaller root
    int pc = parent_s[c];
    if (parent_s[pc] == c && c < pc) parent_s[c] = c;
  }
  __syncthreads();
  for (int it = 0; it < 13; ++it) {    // pointer jumping w/ convergence check
    if (t == 0) chg_s = 0;
    __syncthreads();
    for (int c = t; c < C; c += 1024) {
      int p1 = parent_s[c], p2 = parent_s[p1];
      if (p1 != p2) { parent_s[c] = p2; chg_s = 1; }
    }
    __syncthreads();
    if (!chg_s) break;
  }
  // ---- compact renumber: roots -> dense ranks via markbits + popcount prefix ----
  u16* rank16 = reinterpret_cast<u16*>(cbest_s);   // cbest dead after hook
  int* pre = reinterpret_cast<int*>(cbest_s + 2048);
  if (t < 64) mark64[t] = 0ull;
  __syncthreads();
  for (int c = t; c < C; c += 1024)
    if (parent_s[c] == c) atomicOr(&mark64[c >> 6], 1ull << (c & 63));
  __syncthreads();
  if (t == 0) {
    int run = 0;
    for (int wd = 0; wd < 64; ++wd) { pre[wd] = run; run += __popcll(mark64[wd]); }
    cnt_s = run;
  }
  __syncthreads();
  for (int c = t; c < C; c += 1024)
    if (parent_s[c] == c)
      rank16[c] = (u16)(pre[c >> 6] +
                        __popcll(mark64[c >> 6] & ((1ull << (c & 63)) - 1ull)));
  __syncthreads();
  int cnt = cnt_s;
  for (int v = t; v < NN; v += 1024)
    comp[v] = (int)rank16[parent_s[(int)comp16s[v]]];
  if (t == 0) *ncomp = cnt;
  __syncthreads();
  if (cnt != 1) return;
  // ================== finalize (runs exactly once; R13 verbatim) ==================
  int* rr = reinterpret_cast<int*>(cbest_s);          // 16 KiB: root->rank LUT
  u64* rk = cbest_s + 2048;                           // 8 KiB: reduce keys
  int* rs = reinterpret_cast<int*>(cbest_s + 3072);   // 4 KiB: reduce idx
  int nm = *mstcnt;            // 4095 expected
  if (nm < 0) nm = 0;
  if (nm > 4352) nm = 4352;
  __syncthreads();
  for (int v = t; v < NN; v += 1024) parent_s[v] = v;
  for (int pass = 0; pass < NSUP - 1; ++pass) {       // drop 5 smallest MST edges
    u64 bk = ~0ull; int bsel = -1;
    for (int e = t; e < nm; e += 1024) { u64 k = mkey[e]; if (k < bk) { bk = k; bsel = e; } }
    rk[t] = bk; rs[t] = bsel;
    __syncthreads();
    for (int s = 512; s > 0; s >>= 1) {
      if (t < s && rk[t + s] < rk[t]) { rk[t] = rk[t + s]; rs[t] = rs[t + s]; }
      __syncthreads();
    }
    if (t == 0 && rs[0] >= 0) mkey[rs[0]] = ~0ull;    // mark removed
    __syncthreads();
  }
  for (int round = 0; round < 64; ++round) {          // CC over kept edges
    if (t == 0) changed = 0;
    __syncthreads();
    for (int e = t; e < nm; e += 1024) {
      if (mkey[e] == ~0ull) continue;
      int a = parent_s[mi[e]], b = parent_s[mj[e]];
      if (a == b) continue;
      int m = a < b ? a : b, M = a < b ? b : a;
      int old = atomicMin(&parent_s[M], m);
      if (old > m) changed = 1;
    }
    __syncthreads();
    for (int rep = 0; rep < 3; ++rep) {
      for (int v = t; v < NN; v += 1024) parent_s[v] = parent_s[parent_s[v]];
      __syncthreads();
    }
    int ch = changed;
    __syncthreads();
    if (!ch) break;
  }
  for (int rep = 0; rep < 13; ++rep) {   // full compression -> comp min index
    for (int v = t; v < NN; v += 1024) parent_s[v] = parent_s[parent_s[v]];
    __syncthreads();
  }
  if (t == 0) rcnt = 0;
  __syncthreads();
  for (int v = t; v < NN; v += 1024)
    if (parent_s[v] == v) { int s = atomicAdd(&rcnt, 1); if (s < 16) roots[s] = v; }
  __syncthreads();
  if (t == 0) {                           // sort roots asc == first-occurrence order
    int c = rcnt > 16 ? 16 : rcnt;
    for (int a = 1; a < c; ++a) {
      int x = roots[a]; int b2 = a - 1;
      while (b2 >= 0 && roots[b2] > x) { roots[b2 + 1] = roots[b2]; --b2; }
      roots[b2 + 1] = x;
    }
  }
  if (t < 8) szs[t] = 0;
  __syncthreads();
  if (t < rcnt && t < 16) rr[roots[t]] = t;
  __syncthreads();
  for (int v = t; v < NN; v += 1024) {
    int lab = rr[parent_s[v]];
    labels_g[v] = lab;
    atomicAdd(&szs[lab], 1);
  }
  __syncthreads();
  if (t < rcnt && t < 8) {
    float iv = 1.0f / sqrtf((float)szs[t] + 1e-10f);  // bit-matches reference P
    ivs[t] = iv; invs_g[t] = iv;
  }
  __syncthreads();
  for (int v = t; v < NN; v += 1024) {    // P at out+1572, row-major [4096][6]
    int lab = rr[parent_s[v]];
    float* base = out + 1572 + v * 6;
#pragma unroll
    for (int b2 = 0; b2 < 6; ++b2) base[b2] = (b2 == lab) ? ivs[lab] : 0.0f;
  }
}

// ===== coarse outputs, one kernel: blocks 0-63 X_coarse, 64-79 A_coarse =====
__global__ __launch_bounds__(256) void k_coarse(const float* __restrict__ X,
                                                const u64* __restrict__ bits,
                                                const int* __restrict__ labels,
                                                const float* __restrict__ invs,
                                                float* out) {
  int t = threadIdx.x;
  if (blockIdx.x < 64) {
    __shared__ float acc[6][256];
    __shared__ int labs[64];
    __shared__ float ivl[64];
#pragma unroll
    for (int m = 0; m < 6; ++m) acc[m][t] = 0.0f;
    if (t < 64) { int v = blockIdx.x * 64 + t; int l = labels[v]; labs[t] = l; ivl[t] = invs[l]; }
    __syncthreads();
    int v0 = blockIdx.x * 64;
    for (int r = 0; r < 64; ++r) {
      float x = X[(size_t)(v0 + r) * 256 + t];
      acc[labs[r]][t] += ivl[r] * x;
    }
    __syncthreads();
#pragma unroll
    for (int m = 0; m < 6; ++m) atomicAdd(&out[m * 256 + t], acc[m][t]);
  } else {
    __shared__ unsigned char labs8[NN];   // 4 KiB
    __shared__ float accA[36];
    __shared__ float ivsl[8];
    for (int v = t; v < NN; v += 256) labs8[v] = (unsigned char)labels[v];
    if (t < 36) accA[t] = 0.0f;
    if (t < 6) ivsl[t] = invs[t];
    __syncthreads();
    int i = (blockIdx.x - 64) * 256 + t;
    u64 cnt = 0;   // six 10-bit counters
    const u64* row = bits + (size_t)i * NCH;
    for (int c = 0; c < NCH; ++c) {
      u64 wm = row[c];
      while (wm) {
        int j = (c << 6) + __builtin_ctzll(wm);
        wm &= wm - 1;
        cnt += 1ull << (labs8[j] * 10);
      }
    }
    int li = labs8[i];
    float fi = ivsl[li];
#pragma unroll
    for (int b = 0; b < 6; ++b) {
      float cb = (float)((cnt >> (b * 10)) & 1023ull);
      if (cb != 0.0f) atomicAdd(&accA[li * 6 + b], fi * ivsl[b] * cb);
    }
    __syncthreads();
    if (t < 36) atomicAdd(&out[1536 + t], accA[t]);
  }
}

// ============================ launch ============================
extern "C" void kernel_launch(void* const* d_in, const int* in_sizes, int n_in,
                              void* d_out, int out_size, void* d_ws, size_t ws_size,
                              hipStream_t stream) {
  const float* X = (const float*)d_in[0];
  const float* A = (const float*)d_in[1];
  float* out = (float*)d_out;

  char* wp = (char*)d_ws;
  size_t off = 0;
#define WALLOC(ty, name, count) \
  ty* name = (ty*)(wp + off);   \
  off += (((size_t)(count) * sizeof(ty)) + 255) & ~(size_t)255;
  WALLOC(u64, bits, (size_t)NN * NCH)      // 2 MiB
  WALLOC(u8, inter, (size_t)NN * NN)       // 16 MiB
  WALLOC(u16, deg, NN)
  WALLOC(u64, tk, (size_t)NN * 4)          // 128 KiB top-4 lists
  WALLOC(int, comp, NN)
  WALLOC(u64, nkey, NN)
  WALLOC(int, nu, NN)
  WALLOC(u64, mkey, 4352)
  WALLOC(int, mi, 4352)
  WALLOC(int, mj, 4352)
  WALLOC(int, labels, NN)
  WALLOC(float, invs, 8)
  WALLOC(int, ncomp, 1)
  WALLOC(int, mstcnt, 1)
#undef WALLOC
  if (off > ws_size) return;   // workspace too small: leave output zeroed (clean fail)

  k_packdeg<<<NN / 4, 256, 0, stream>>>(A, bits, deg, out, out_size, comp, ncomp, mstcnt);
  k_inter<<<2080, 256, 0, stream>>>(bits, inter);
  k_scan0<<<NN / 4, 256, 0, stream>>>(inter, deg, tk, nkey, nu);
  for (int ph = 0; ph < 12; ++ph) {
    k_merge<<<1, 1024, 0, stream>>>(nkey, nu, comp, ncomp, mstcnt, mkey, mi, mj,
                                    labels, invs, out);
    if (ph < 11)
      k_scan<<<NN / 4, 256, 0, stream>>>(inter, deg, tk, comp, ncomp, nkey, nu);
  }
  k_coarse<<<80, 256, 0, stream>>>(X, bits, labels, invs, out);
}

// Round 16
// 336.657 us; speedup vs baseline: 1.0228x; 1.0228x over previous
//
#include <hip/hip_runtime.h>

typedef unsigned long long u64;
typedef unsigned short u16;
typedef unsigned char u8;

#define NN 4096
#define NCH 64          // u64 chunks per bit-row
#define NSUP 6

// global pair key: (sim bits << 24) | (0xFFFFFF - triangular pair index)
__device__ __forceinline__ u64 gkey(int v, int u, unsigned sb) {
  int i = v < u ? v : u, j = v < u ? u : v;
  unsigned idx = (unsigned)i * (unsigned)(2 * NN - i - 1) / 2u + (unsigned)(j - i - 1);
  return ((u64)sb << 24) | (u64)(0xFFFFFFu - idx);
}

// insert kk into sorted-descending {a0>=a1>=a2>=a3} (keys unique)
__device__ __forceinline__ void ins4(u64& a0, u64& a1, u64& a2, u64& a3, u64 kk) {
  bool g0 = kk > a0, g1 = kk > a1, g2 = kk > a2, g3 = kk > a3;
  a3 = g3 ? (g2 ? a2 : kk) : a3;
  a2 = g2 ? (g1 ? a1 : kk) : a2;
  a1 = g1 ? (g0 ? a0 : kk) : a1;
  a0 = g0 ? kk : a0;
}

// ========= pack A rows into bits + degree (ballot) + all init, fused =========
__global__ __launch_bounds__(256) void k_packdeg(const float* __restrict__ A,
                                                 u64* __restrict__ bits,
                                                 u16* __restrict__ deg,
                                                 float* out, int out_n,
                                                 int* comp, int* ncomp, int* mstcnt) {
  int t = threadIdx.x;
  int w = t >> 6, lane = t & 63;
  int row = blockIdx.x * 4 + w;
  const float* rp = A + (size_t)row * NN;
  u64 my = 0;
  int dsum = 0;
#pragma unroll 8
  for (int k = 0; k < 64; ++k) {
    float v = rp[k * 64 + lane];
    u64 m = __ballot(v > 0.0f);
    dsum += __popcll(m);
    if (lane == k) my = m;
  }
  bits[(size_t)row * NCH + lane] = my;
  if (lane == 0) deg[row] = (u16)dsum;
  int g = blockIdx.x * 256 + t;
  if (g < out_n) out[g] = 0.0f;            // out_n = 26148
  if (g < NN) comp[g] = g;
  if (g == 0) { *ncomp = NN; *mstcnt = 0; }
}

// ========== inter[i][j] = |N(i) & N(j)| via popcount GEMM (u8, R8-proven) ==========
__global__ __launch_bounds__(256) void k_inter(const u64* __restrict__ bits,
                                               u8* __restrict__ inter) {
  __shared__ ulonglong2 L[2][64 * 16];   // 32 KiB total
  int b = blockIdx.x;
  int by = (int)((129.0f - sqrtf(16641.0f - 8.0f * (float)b)) * 0.5f) - 1;
  if (by < 0) by = 0;
#define CUM(y) (64 * (y) - ((y) * ((y) - 1)) / 2)
  while (by < 63 && CUM(by + 1) <= b) ++by;
  while (CUM(by) > b) --by;
  int bx = by + (b - CUM(by));
#undef CUM
  int i0 = by * 64, j0 = bx * 64;
  int t = threadIdx.x;
  int tx = t & 15, ty = t >> 4;
  int rowA[4], swA[4], rowB[4], swB[4];
#pragma unroll
  for (int a = 0; a < 4; ++a) {
    rowA[a] = ty * 4 + a; swA[a] = (rowA[a] ^ (rowA[a] >> 2)) & 7;
    rowB[a] = tx * 4 + a; swB[a] = (rowB[a] ^ (rowB[a] >> 2)) & 7;
  }
  int cuL = t & 15, rg = t >> 4;
  int acc[4][4] = {};
  for (int st = 0; st < 2; ++st) {
    __syncthreads();
#pragma unroll
    for (int rr = 0; rr < 4; ++rr) {
      int row = rg * 4 + rr;
      int sw = (row ^ (row >> 2)) & 7;
      L[0][row * 16 + (cuL ^ sw)] =
          reinterpret_cast<const ulonglong2*>(bits + (size_t)(i0 + row) * NCH)[st * 16 + cuL];
      L[1][row * 16 + (cuL ^ sw)] =
          reinterpret_cast<const ulonglong2*>(bits + (size_t)(j0 + row) * NCH)[st * 16 + cuL];
    }
    __syncthreads();
    for (int cu = 0; cu < 16; ++cu) {
      ulonglong2 av[4], bv[4];
#pragma unroll
      for (int a = 0; a < 4; ++a) av[a] = L[0][rowA[a] * 16 + (cu ^ swA[a])];
#pragma unroll
      for (int b2 = 0; b2 < 4; ++b2) bv[b2] = L[1][rowB[b2] * 16 + (cu ^ swB[b2])];
#pragma unroll
      for (int a = 0; a < 4; ++a)
#pragma unroll
        for (int b2 = 0; b2 < 4; ++b2)
          acc[a][b2] += __popcll(av[a].x & bv[b2].x) + __popcll(av[a].y & bv[b2].y);
    }
  }
#pragma unroll
  for (int a = 0; a < 4; ++a) {
    int i = i0 + ty * 4 + a;
    uchar4 wv;
    wv.x = (u8)acc[a][0]; wv.y = (u8)acc[a][1];
    wv.z = (u8)acc[a][2]; wv.w = (u8)acc[a][3];
    *reinterpret_cast<uchar4*>(inter + (size_t)i * NN + j0 + tx * 4) = wv;
  }
  if (bx != by) {
#pragma unroll
    for (int b2 = 0; b2 < 4; ++b2) {
      int j = j0 + tx * 4 + b2;
      uchar4 wv;
      wv.x = (u8)acc[0][b2]; wv.y = (u8)acc[1][b2];
      wv.z = (u8)acc[2][b2]; wv.w = (u8)acc[3][b2];
      *reinterpret_cast<uchar4*>(inter + (size_t)j * NN + i0 + ty * 4) = wv;
    }
  }
}

// ===== scan0: exact per-node TOP-4 list + phase-0 nkey/nu (one wave/row) =====
__global__ __launch_bounds__(256) void k_scan0(const u8* __restrict__ inter,
                                               const u16* __restrict__ deg,
                                               u64* __restrict__ tk,
                                               u64* __restrict__ nkey,
                                               int* __restrict__ nu) {
  __shared__ u16 deg_s[NN];    // 8 KiB
  int t = threadIdx.x;
  for (int i = t; i < NN / 8; i += 256)
    reinterpret_cast<uint4*>(deg_s)[i] = reinterpret_cast<const uint4*>(deg)[i];
  __syncthreads();
  int w = t >> 6, lane = t & 63;
  int v = blockIdx.x * 4 + w;
  int dv = (int)deg_s[v];
  const u8* row = inter + (size_t)v * NN;
  u64 a0 = 0, a1 = 0, a2 = 0, a3 = 0;
  for (int it = 0; it < 4; ++it) {
    int ub = it * 1024 + lane * 16;
    uint4 pv = *reinterpret_cast<const uint4*>(row + ub);              // 16x u8 inter
    uint4 dg0 = reinterpret_cast<const uint4*>(deg_s)[ub >> 3];
    uint4 dg1 = reinterpret_cast<const uint4*>(deg_s)[(ub >> 3) + 1];
    unsigned pw[4] = { pv.x, pv.y, pv.z, pv.w };
    unsigned dw[8] = { dg0.x, dg0.y, dg0.z, dg0.w, dg1.x, dg1.y, dg1.z, dg1.w };
#pragma unroll
    for (int k = 0; k < 16; ++k) {
      int u = ub + k;
      int iv = (int)((pw[k >> 2] >> ((k & 3) * 8)) & 0xFF);
      int du = (int)((dw[k >> 1] >> ((k & 1) * 16)) & 0xFFFF);
      int un = dv + du - iv;
      float s = (un > 0) ? ((float)iv / (float)un) : 0.0f;             // exact fp32 div == numpy
      u64 kk = (u != v)
                   ? (((u64)__float_as_uint(s) << 32) | (u64)(0xFFFFFFFFu - (unsigned)u))
                   : 0ull;
      ins4(a0, a1, a2, a3, kk);
    }
  }
#pragma unroll
  for (int off = 1; off < 64; off <<= 1) {   // wave butterfly merge of top4 lists
    u64 b0 = __shfl_xor(a0, off, 64);
    u64 b1 = __shfl_xor(a1, off, 64);
    u64 b2 = __shfl_xor(a2, off, 64);
    u64 b3 = __shfl_xor(a3, off, 64);
    ins4(a0, a1, a2, a3, b0);
    ins4(a0, a1, a2, a3, b1);
    ins4(a0, a1, a2, a3, b2);
    ins4(a0, a1, a2, a3, b3);
  }
  if (lane == 0) {
    u64* tv = tk + (size_t)v * 4;
    tv[0] = a0; tv[1] = a1; tv[2] = a2; tv[3] = a3;
    int u0 = (int)(0xFFFFFFFFu - (unsigned)(a0 & 0xFFFFFFFFull));
    nkey[v] = gkey(v, u0, (unsigned)(a0 >> 32));
    nu[v] = u0;
  }
}

// ===== loop scan (ph>=1): lean top-4 check vs global comp; stage only if stale =====
__global__ __launch_bounds__(256) void k_scan(const u8* __restrict__ inter,
                                              const u16* __restrict__ deg,
                                              const u64* __restrict__ tk,
                                              const int* __restrict__ comp,
                                              const int* __restrict__ ncomp,
                                              u64* __restrict__ nkey,
                                              int* __restrict__ nu) {
  if (*ncomp <= 1) return;
  __shared__ u16 comp_s[NN];   // 8 KiB (staged only when stale)
  __shared__ u16 deg_s[NN];    // 8 KiB
  __shared__ int needflag;
  int t = threadIdx.x;
  int w = t >> 6, lane = t & 63;
  int v = blockIdx.x * 4 + w;
  if (t == 0) needflag = 0;
  __syncthreads();
  if (lane == 0) {
    int cv = comp[v];
    const u64* tv = tk + (size_t)v * 4;
    u64 gk = 0; int bu = -1;
#pragma unroll
    for (int e = 0; e < 4; ++e) {
      u64 cand = tv[e];
      unsigned uu = 0xFFFFFFFFu - (unsigned)(cand & 0xFFFFFFFFull);
      if (bu < 0 && comp[uu] != cv) {
        bu = (int)uu;
        gk = gkey(v, (int)uu, (unsigned)(cand >> 32));
      }
    }
    if (bu >= 0) { nkey[v] = gk; nu[v] = bu; }
    else atomicOr(&needflag, 1 << w);
  }
  __syncthreads();
  int needmask = needflag;
  if (!needmask) return;
  // --- stale path: stage comp(u16)+deg, exact full-row rescan (R8 body) ---
  for (int i = t; i < NN / 8; i += 256) {
    int4 ca = reinterpret_cast<const int4*>(comp)[i * 2];
    int4 cb = reinterpret_cast<const int4*>(comp)[i * 2 + 1];
    uint4 pk;
    pk.x = (unsigned)ca.x | ((unsigned)ca.y << 16);
    pk.y = (unsigned)ca.z | ((unsigned)ca.w << 16);
    pk.z = (unsigned)cb.x | ((unsigned)cb.y << 16);
    pk.w = (unsigned)cb.z | ((unsigned)cb.w << 16);
    reinterpret_cast<uint4*>(comp_s)[i] = pk;
    reinterpret_cast<uint4*>(deg_s)[i] = reinterpret_cast<const uint4*>(deg)[i];
  }
  __syncthreads();
  if (!(needmask >> w & 1)) return;
  int cv = (int)comp_s[v];
  int dv = (int)deg_s[v];
  const u8* row = inter + (size_t)v * NN;
  u64 key = 0;
  for (int it = 0; it < 4; ++it) {
    int ub = it * 1024 + lane * 16;
    uint4 pv = *reinterpret_cast<const uint4*>(row + ub);              // 16x u8 inter
    uint4 dg0 = reinterpret_cast<const uint4*>(deg_s)[ub >> 3];
    uint4 dg1 = reinterpret_cast<const uint4*>(deg_s)[(ub >> 3) + 1];
    uint4 cs0 = reinterpret_cast<const uint4*>(comp_s)[ub >> 3];
    uint4 cs1 = reinterpret_cast<const uint4*>(comp_s)[(ub >> 3) + 1];
    unsigned pw[4] = { pv.x, pv.y, pv.z, pv.w };
    unsigned dw[8] = { dg0.x, dg0.y, dg0.z, dg0.w, dg1.x, dg1.y, dg1.z, dg1.w };
    unsigned cw[8] = { cs0.x, cs0.y, cs0.z, cs0.w, cs1.x, cs1.y, cs1.z, cs1.w };
#pragma unroll
    for (int k = 0; k < 16; ++k) {
      int iv = (int)((pw[k >> 2] >> ((k & 3) * 8)) & 0xFF);
      int du = (int)((dw[k >> 1] >> ((k & 1) * 16)) & 0xFFFF);
      int cu = (int)((cw[k >> 1] >> ((k & 1) * 16)) & 0xFFFF);
      int un = dv + du - iv;
      float s = (un > 0) ? ((float)iv / (float)un) : 0.0f;             // exact fp32 div == numpy
      u64 kk = (cu != cv)
                   ? (((u64)__float_as_uint(s) << 32) | (u64)(0xFFFFFFFFu - (unsigned)(ub + k)))
                   : 0ull;
      if (kk > key) key = kk;
    }
  }
#pragma unroll
  for (int off = 32; off > 0; off >>= 1) {                              // wave max-reduce
    unsigned lo = (unsigned)key, hi = (unsigned)(key >> 32);
    unsigned olo = __shfl_xor(lo, off, 64), ohi = __shfl_xor(hi, off, 64);
    u64 o = ((u64)ohi << 32) | (u64)olo;
    if (o > key) key = o;
  }
  if (lane == 0) {
    u64 pk = 0; int u = -1;
    if (key != 0ull) {
      unsigned simb = (unsigned)(key >> 32);
      u = (int)(0xFFFFFFFFu - (unsigned)(key & 0xFFFFFFFFull));
      pk = gkey(v, u, simb);
    }
    nkey[v] = pk; nu[v] = u;
  }
}

// ===== Boruvka merge: 1024 threads, COMPACT component ids (R14-proven) =====
__global__ __launch_bounds__(1024) void k_merge(const u64* __restrict__ nkey,
                                                const int* __restrict__ nu,
                                                int* comp, int* ncomp, int* mstcnt,
                                                u64* mkey, int* mi, int* mj,
                                                int* labels_g, float* invs_g, float* out) {
  int C = *ncomp;
  if (C <= 1) return;
  __shared__ int parent_s[NN];        // 16 KiB (finalize: p[])
  __shared__ u64 cbest_s[NN];         // 32 KiB (later: rank16/pre; finalize: rr/rk/rs)
  __shared__ u16 comp16s[NN];         // 8 KiB
  __shared__ u64 mark64[64];
  __shared__ int roots[16];
  __shared__ int rcnt, cnt_s, chg_s, changed;
  __shared__ int szs[8];
  __shared__ float ivs[8];
  int t = threadIdx.x;
  for (int i = t; i < NN / 8; i += 1024) {   // stage comp as u16
    int4 ca = reinterpret_cast<const int4*>(comp)[i * 2];
    int4 cb = reinterpret_cast<const int4*>(comp)[i * 2 + 1];
    uint4 pk;
    pk.x = (unsigned)ca.x | ((unsigned)ca.y << 16);
    pk.y = (unsigned)ca.z | ((unsigned)ca.w << 16);
    pk.z = (unsigned)cb.x | ((unsigned)cb.y << 16);
    pk.w = (unsigned)cb.z | ((unsigned)cb.w << 16);
    reinterpret_cast<uint4*>(comp16s)[i] = pk;
  }
  for (int c = t; c < C; c += 1024) { parent_s[c] = c; cbest_s[c] = 0ull; }
  __syncthreads();
  for (int v = t; v < NN; v += 1024) {
    u64 k = nkey[v];
    if (k) atomicMax(&cbest_s[(int)comp16s[v]], k);
  }
  __syncthreads();
  for (int v = t; v < NN; v += 1024) {
    u64 k = nkey[v];
    if (!k) continue;
    int c = (int)comp16s[v];
    if (k == cbest_s[c]) {
      int u = nu[v];
      int cu = (int)comp16s[u];
      bool mutual = (cbest_s[cu] == k);
      if (!mutual || v < u) {
        int slot = atomicAdd(mstcnt, 1);
        if (slot < 4352) { mkey[slot] = k; mi[slot] = v; mj[slot] = u; }
      }
      parent_s[c] = cu;                // one winner per component (keys unique)
    }
  }
  __syncthreads();
  for (int c = t; c < C; c += 1024) {  // break mutual 2-cycles: keep smaller root
    int pc = parent_s[c];
    if (parent_s[pc] == c && c < pc) parent_s[c] = c;
  }
  __syncthreads();
  for (int it = 0; it < 13; ++it) {    // pointer jumping w/ convergence check
    if (t == 0) chg_s = 0;
    __syncthreads();
    for (int c = t; c < C; c += 1024) {
      int p1 = parent_s[c], p2 = parent_s[p1];
      if (p1 != p2) { parent_s[c] = p2; chg_s = 1; }
    }
    __syncthreads();
    if (!chg_s) break;
  }
  // ---- compact renumber: roots -> dense ranks via markbits + popcount prefix ----
  u16* rank16 = reinterpret_cast<u16*>(cbest_s);   // cbest dead after hook
  int* pre = reinterpret_cast<int*>(cbest_s + 2048);
  if (t < 64) mark64[t] = 0ull;
  __syncthreads();
  for (int c = t; c < C; c += 1024)
    if (parent_s[c] == c) atomicOr(&mark64[c >> 6], 1ull << (c & 63));
  __syncthreads();
  if (t == 0) {
    int run = 0;
    for (int wd = 0; wd < 64; ++wd) { pre[wd] = run; run += __popcll(mark64[wd]); }
    cnt_s = run;
  }
  __syncthreads();
  for (int c = t; c < C; c += 1024)
    if (parent_s[c] == c)
      rank16[c] = (u16)(pre[c >> 6] +
                        __popcll(mark64[c >> 6] & ((1ull << (c & 63)) - 1ull)));
  __syncthreads();
  int cnt = cnt_s;
  for (int v = t; v < NN; v += 1024)
    comp[v] = (int)rank16[parent_s[(int)comp16s[v]]];
  if (t == 0) *ncomp = cnt;
  __syncthreads();
  if (cnt != 1) return;
  // ================== finalize (runs exactly once; R13 verbatim) ==================
  int* rr = reinterpret_cast<int*>(cbest_s);          // 16 KiB: root->rank LUT
  u64* rk = cbest_s + 2048;                           // 8 KiB: reduce keys
  int* rs = reinterpret_cast<int*>(cbest_s + 3072);   // 4 KiB: reduce idx
  int nm = *mstcnt;            // 4095 expected
  if (nm < 0) nm = 0;
  if (nm > 4352) nm = 4352;
  __syncthreads();
  for (int v = t; v < NN; v += 1024) parent_s[v] = v;
  for (int pass = 0; pass < NSUP - 1; ++pass) {       // drop 5 smallest MST edges
    u64 bk = ~0ull; int bsel = -1;
    for (int e = t; e < nm; e += 1024) { u64 k = mkey[e]; if (k < bk) { bk = k; bsel = e; } }
    rk[t] = bk; rs[t] = bsel;
    __syncthreads();
    for (int s = 512; s > 0; s >>= 1) {
      if (t < s && rk[t + s] < rk[t]) { rk[t] = rk[t + s]; rs[t] = rs[t + s]; }
      __syncthreads();
    }
    if (t == 0 && rs[0] >= 0) mkey[rs[0]] = ~0ull;    // mark removed
    __syncthreads();
  }
  for (int round = 0; round < 64; ++round) {          // CC over kept edges
    if (t == 0) changed = 0;
    __syncthreads();
    for (int e = t; e < nm; e += 1024) {
      if (mkey[e] == ~0ull) continue;
      int a = parent_s[mi[e]], b = parent_s[mj[e]];
      if (a == b) continue;
      int m = a < b ? a : b, M = a < b ? b : a;
      int old = atomicMin(&parent_s[M], m);
      if (old > m) changed = 1;
    }
    __syncthreads();
    for (int rep = 0; rep < 3; ++rep) {
      for (int v = t; v < NN; v += 1024) parent_s[v] = parent_s[parent_s[v]];
      __syncthreads();
    }
    int ch = changed;
    __syncthreads();
    if (!ch) break;
  }
  for (int rep = 0; rep < 13; ++rep) {   // full compression -> comp min index
    for (int v = t; v < NN; v += 1024) parent_s[v] = parent_s[parent_s[v]];
    __syncthreads();
  }
  if (t == 0) rcnt = 0;
  __syncthreads();
  for (int v = t; v < NN; v += 1024)
    if (parent_s[v] == v) { int s = atomicAdd(&rcnt, 1); if (s < 16) roots[s] = v; }
  __syncthreads();
  if (t == 0) {                           // sort roots asc == first-occurrence order
    int c = rcnt > 16 ? 16 : rcnt;
    for (int a = 1; a < c; ++a) {
      int x = roots[a]; int b2 = a - 1;
      while (b2 >= 0 && roots[b2] > x) { roots[b2 + 1] = roots[b2]; --b2; }
      roots[b2 + 1] = x;
    }
  }
  if (t < 8) szs[t] = 0;
  __syncthreads();
  if (t < rcnt && t < 16) rr[roots[t]] = t;
  __syncthreads();
  for (int v = t; v < NN; v += 1024) {
    int lab = rr[parent_s[v]];
    labels_g[v] = lab;
    atomicAdd(&szs[lab], 1);
  }
  __syncthreads();
  if (t < rcnt && t < 8) {
    float iv = 1.0f / sqrtf((float)szs[t] + 1e-10f);  // bit-matches reference P
    ivs[t] = iv; invs_g[t] = iv;
  }
  __syncthreads();
  for (int v = t; v < NN; v += 1024) {    // P at out+1572, row-major [4096][6]
    int lab = rr[parent_s[v]];
    float* base = out + 1572 + v * 6;
#pragma unroll
    for (int b2 = 0; b2 < 6; ++b2) base[b2] = (b2 == lab) ? ivs[lab] : 0.0f;
  }
}

// ===== coarse outputs, one kernel: blocks 0-63 X_coarse, 64-79 A_coarse =====
__global__ __launch_bounds__(256) void k_coarse(const float* __restrict__ X,
                                                const u64* __restrict__ bits,
                                                const int* __restrict__ labels,
                                                const float* __restrict__ invs,
                                                float* out) {
  int t = threadIdx.x;
  if (blockIdx.x < 64) {
    __shared__ float acc[6][256];
    __shared__ int labs[64];
    __shared__ float ivl[64];
#pragma unroll
    for (int m = 0; m < 6; ++m) acc[m][t] = 0.0f;
    if (t < 64) { int v = blockIdx.x * 64 + t; int l = labels[v]; labs[t] = l; ivl[t] = invs[l]; }
    __syncthreads();
    int v0 = blockIdx.x * 64;
    for (int r = 0; r < 64; ++r) {
      float x = X[(size_t)(v0 + r) * 256 + t];
      acc[labs[r]][t] += ivl[r] * x;
    }
    __syncthreads();
#pragma unroll
    for (int m = 0; m < 6; ++m) atomicAdd(&out[m * 256 + t], acc[m][t]);
  } else {
    __shared__ unsigned char labs8[NN];   // 4 KiB
    __shared__ float accA[36];
    __shared__ float ivsl[8];
    for (int v = t; v < NN; v += 256) labs8[v] = (unsigned char)labels[v];
    if (t < 36) accA[t] = 0.0f;
    if (t < 6) ivsl[t] = invs[t];
    __syncthreads();
    int i = (blockIdx.x - 64) * 256 + t;
    u64 cnt = 0;   // six 10-bit counters
    const u64* row = bits + (size_t)i * NCH;
    for (int c = 0; c < NCH; ++c) {
      u64 wm = row[c];
      while (wm) {
        int j = (c << 6) + __builtin_ctzll(wm);
        wm &= wm - 1;
        cnt += 1ull << (labs8[j] * 10);
      }
    }
    int li = labs8[i];
    float fi = ivsl[li];
#pragma unroll
    for (int b = 0; b < 6; ++b) {
      float cb = (float)((cnt >> (b * 10)) & 1023ull);
      if (cb != 0.0f) atomicAdd(&accA[li * 6 + b], fi * ivsl[b] * cb);
    }
    __syncthreads();
    if (t < 36) atomicAdd(&out[1536 + t], accA[t]);
  }
}

// ============================ launch ============================
extern "C" void kernel_launch(void* const* d_in, const int* in_sizes, int n_in,
                              void* d_out, int out_size, void* d_ws, size_t ws_size,
                              hipStream_t stream) {
  const float* X = (const float*)d_in[0];
  const float* A = (const float*)d_in[1];
  float* out = (float*)d_out;

  char* wp = (char*)d_ws;
  size_t off = 0;
#define WALLOC(ty, name, count) \
  ty* name = (ty*)(wp + off);   \
  off += (((size_t)(count) * sizeof(ty)) + 255) & ~(size_t)255;
  WALLOC(u64, bits, (size_t)NN * NCH)      // 2 MiB
  WALLOC(u8, inter, (size_t)NN * NN)       // 16 MiB
  WALLOC(u16, deg, NN)
  WALLOC(u64, tk, (size_t)NN * 4)          // 128 KiB top-4 lists
  WALLOC(int, comp, NN)
  WALLOC(u64, nkey, NN)
  WALLOC(int, nu, NN)
  WALLOC(u64, mkey, 4352)
  WALLOC(int, mi, 4352)
  WALLOC(int, mj, 4352)
  WALLOC(int, labels, NN)
  WALLOC(float, invs, 8)
  WALLOC(int, ncomp, 1)
  WALLOC(int, mstcnt, 1)
#undef WALLOC
  if (off > ws_size) return;   // workspace too small: leave output zeroed (clean fail)

  k_packdeg<<<NN / 4, 256, 0, stream>>>(A, bits, deg, out, out_size, comp, ncomp, mstcnt);
  k_inter<<<2080, 256, 0, stream>>>(bits, inter);
  k_scan0<<<NN / 4, 256, 0, stream>>>(inter, deg, tk, nkey, nu);
  for (int ph = 0; ph < 12; ++ph) {
    k_merge<<<1, 1024, 0, stream>>>(nkey, nu, comp, ncomp, mstcnt, mkey, mi, mj,
                                    labels, invs, out);
    if (ph < 11)
      k_scan<<<NN / 4, 256, 0, stream>>>(inter, deg, tk, comp, ncomp, nkey, nu);
  }
  k_coarse<<<80, 256, 0, stream>>>(X, bits, labels, invs, out);
}